// Round 9
// baseline (441.553 us; speedup 1.0000x reference)
//
#include <hip/hip_runtime.h>
#include <hip/hip_bf16.h>
#include <hip/hip_fp16.h>
#include <math.h>

#define NATOMS 16384
#define NEDGE  524288
#define NINT   6
#define NGAUSS 50
#define TK     2048
#define INV_DT 128.0f    // knots at d = k/128, range [0,16)
#define DT     (1.0f/128.0f)
#define LOG2F_ 0.69314718055994530942f
#define NBUCK  512       // per graph, 32 dst atoms each

typedef _Float16 h2    __attribute__((ext_vector_type(2)));
typedef _Float16 f16x8 __attribute__((ext_vector_type(8)));
typedef float    f32x4 __attribute__((ext_vector_type(4)));

__device__ __forceinline__ float sspf(float v){
    return fmaxf(v, 0.f) + log1pf(__expf(-fabsf(v))) - LOG2F_;
}

// ---------------- h = emb[z]  (rows 0..N-1 = A, N..2N-1 = G)
__global__ __launch_bounds__(256) void k_embed(const int* __restrict__ zA, const int* __restrict__ zG,
                                               const float* __restrict__ emb, float* __restrict__ h){
    int idx = blockIdx.x * 256 + threadIdx.x;        // < 2*NATOMS*64
    int n = idx >> 6, f = idx & 63;
    int z = (n < NATOMS) ? zA[n] : zG[n - NATOMS];
    h[idx] = emb[(z << 6) + f];
}

// ---------------- bucket histogram (LDS-privatized, coalesced global adds)
__global__ __launch_bounds__(256) void k_bhist(const int* __restrict__ edgeA, const int* __restrict__ edgeG,
                                               int* __restrict__ bhist){
    __shared__ int lh[NBUCK];
    int blk = blockIdx.x;                    // 256: 0-127 graph A, 128-255 graph G
    int g   = blk >> 7;
    int e0  = (blk & 127) * 4096;
    const int* dst = (g ? edgeG : edgeA) + NEDGE;
    int t = threadIdx.x;
    lh[t] = 0; lh[t + 256] = 0;
    __syncthreads();
    #pragma unroll
    for (int j = 0; j < 16; j++){
        int d = dst[e0 + j * 256 + t];
        atomicAdd(&lh[d >> 5], 1);
    }
    __syncthreads();
    atomicAdd(&bhist[g * NBUCK + t],       lh[t]);
    atomicAdd(&bhist[g * NBUCK + 256 + t], lh[t + 256]);
}

// ---------------- bucket exclusive scan -> bstart (513/graph) + gcur init
__global__ __launch_bounds__(512) void k_bscan(const int* __restrict__ bhist, int* __restrict__ bstart,
                                               int* __restrict__ gcur){
    int g = blockIdx.x;
    __shared__ int s[NBUCK];
    int t = threadIdx.x;
    int v = bhist[g * NBUCK + t];
    s[t] = v;
    __syncthreads();
    for (int off = 1; off < NBUCK; off <<= 1){
        int a = (t >= off) ? s[t - off] : 0;
        __syncthreads();
        s[t] += a;
        __syncthreads();
    }
    int ex = s[t] - v;
    bstart[g * (NBUCK + 1) + t] = ex;
    gcur[g * NBUCK + t] = ex;
    if (t == NBUCK - 1) bstart[g * (NBUCK + 1) + NBUCK] = s[NBUCK - 1];
}

// ---------------- pass 1: bucket-binned placement (coherent writes)
__global__ __launch_bounds__(256) void k_place1(const int* __restrict__ edgeA, const int* __restrict__ edgeG,
                                                const float* __restrict__ posA, const float* __restrict__ posG,
                                                int* __restrict__ gcur, uint2* __restrict__ meta8){
    __shared__ unsigned int lhist[NBUCK];
    __shared__ unsigned int lbase[NBUCK];
    int blk = blockIdx.x;
    int g   = blk >> 7;
    int el0 = (blk & 127) * 4096;
    const int* edge = g ? edgeG : edgeA;
    const float* pos = g ? posG : posA;
    int t = threadIdx.x;
    lhist[t] = 0; lhist[t + 256] = 0;
    __syncthreads();
    unsigned int  mx[16]; float my[16];
    unsigned short rk[16]; unsigned short bb[16];
    #pragma unroll
    for (int j = 0; j < 16; j++){
        int el = el0 + j * 256 + t;
        int src = edge[el], dst = edge[NEDGE + el];
        float dx = pos[src*3+0] - pos[dst*3+0];
        float dy = pos[src*3+1] - pos[dst*3+1];
        float dz = pos[src*3+2] - pos[dst*3+2];
        float d  = sqrtf(fmaf(dx,dx, fmaf(dy,dy, fmaf(dz,dz, 1e-12f))));
        float tp = d * INV_DT;
        int   ti = (int)tp; if (ti > TK - 2) ti = TK - 2;
        float tf = tp - (float)ti;
        int b = dst >> 5;
        bb[j] = (unsigned short)b;
        rk[j] = (unsigned short)atomicAdd(&lhist[b], 1u);
        mx[j] = (unsigned int)src | ((unsigned int)ti << 14) | ((unsigned int)(dst & 31) << 25);
        my[j] = tf;
    }
    __syncthreads();
    lbase[t]       = (unsigned int)atomicAdd(&gcur[g * NBUCK + t],       (int)lhist[t]);
    lbase[t + 256] = (unsigned int)atomicAdd(&gcur[g * NBUCK + t + 256], (int)lhist[t + 256]);
    __syncthreads();
    #pragma unroll
    for (int j = 0; j < 16; j++){
        unsigned int pos_ = lbase[bb[j]] + rk[j];
        meta8[(size_t)g * NEDGE + pos_] = make_uint2(mx[j], __float_as_uint(my[j]));
    }
}

// ---------------- pass 2: per-bucket rowptr build + per-dst scatter (L2-hot)
// metaF: m.x = srcElem(20 = src<<6) | ti<<20(11) ; m.y = half2(1-tf, tf)
__global__ __launch_bounds__(256) void k_place2(const uint2* __restrict__ meta8, const int* __restrict__ bstart,
                                                int* __restrict__ rowptr, uint2* __restrict__ metaF){
    __shared__ int lcnt[32];
    __shared__ int lcur[32];
    int blk = blockIdx.x;
    int g = blk >> 9;
    int b = blk & (NBUCK - 1);
    int lo = bstart[g * (NBUCK + 1) + b];
    int hi = bstart[g * (NBUCK + 1) + b + 1];
    int t = threadIdx.x;
    if (t < 32) lcnt[t] = 0;
    __syncthreads();
    for (int idx = lo + t; idx < hi; idx += 256){
        uint2 m = meta8[(size_t)g * NEDGE + idx];
        atomicAdd(&lcnt[(m.x >> 25) & 31u], 1);
    }
    __syncthreads();
    if (t == 0){
        int run = lo;
        int* rp = rowptr + g * (NATOMS + 1) + (b << 5);
        #pragma unroll
        for (int i = 0; i < 32; i++){
            int c = lcnt[i];
            lcur[i] = run;
            rp[i] = run;
            run += c;
        }
        if (b == NBUCK - 1) rowptr[g * (NATOMS + 1) + NATOMS] = hi;
    }
    __syncthreads();
    for (int idx = lo + t; idx < hi; idx += 256){
        uint2 m = meta8[(size_t)g * NEDGE + idx];
        int dl = (int)((m.x >> 25) & 31u);
        int p = atomicAdd(&lcur[dl], 1);
        float tf = __uint_as_float(m.y);
        h2 t2; t2.x = (_Float16)(1.0f - tf); t2.y = (_Float16)tf;
        unsigned int src = m.x & 16383u;
        unsigned int ti  = (m.x >> 14) & 2047u;
        metaF[(size_t)g * NEDGE + p] = make_uint2((src << 6) | (ti << 20),
                                                  __builtin_bit_cast(unsigned int, t2));
    }
}

// ---------------- tabulate W_i(d)*C(d) on TK knots (fp32 scratch)
__global__ __launch_bounds__(256) void k_tables(const float* __restrict__ mw1, const float* __restrict__ mb1,
                                                const float* __restrict__ mw2, const float* __restrict__ mb2,
                                                float* __restrict__ tabf){
    int wv   = blockIdx.x * 4 + (threadIdx.x >> 6);
    int lane = threadIdx.x & 63;
    int i = wv >> 11, k = wv & (TK - 1);
    float d = (float)k * DT;
    const float step  = 10.0f / 49.0f;
    const float coeff = -0.5f / (step * step);
    float u = mb1[(i << 6) + lane];
    #pragma unroll
    for (int gg = 0; gg < NGAUSS; gg++){
        float od = d - (float)gg * step;
        float ea = __expf(coeff * od * od);
        u = fmaf(ea, mw1[((i * NGAUSS + gg) << 6) + lane], u);
    }
    float t = sspf(u);
    float w = mb2[(i << 6) + lane];
    #pragma unroll
    for (int gg = 0; gg < 64; gg++){
        float tg = __shfl(t, gg, 64);
        w = fmaf(tg, mw2[(((i << 6) + gg) << 6) + lane], w);
    }
    float cc = 0.5f * (__cosf(d * 0.31415926535897932f) + 1.0f);
    tabf[((size_t)(i * TK + k) << 6) + lane] = w * cc;
}

// ---------------- pack interleaved half2 table: tab2[k][lane] = (Wk, Wk+1)
__global__ __launch_bounds__(256) void k_pack(const float* __restrict__ tabf, __half2* __restrict__ tab2){
    size_t idx = (size_t)blockIdx.x * 256 + threadIdx.x;
    size_t rem = idx & ((size_t)TK * 64 - 1);
    float a = tabf[idx];
    float b = (rem < (size_t)TK * 64 - 64) ? tabf[idx + 64] : a;
    tab2[idx] = __floats2half2_rn(a, b);
}

// ---------------- pack 18 weight matrices transposed to fp16: wT[s][c][k] = w_s[k][c]
__global__ __launch_bounds__(256) void k_wpack(const float* __restrict__ l1w, const float* __restrict__ l2w,
                                               const float* __restrict__ l3w, __half* __restrict__ wT){
    int idx = blockIdx.x * 256 + threadIdx.x;   // < 18*4096
    int s = idx >> 12;
    int r = idx & 4095;
    int c = r >> 6, k = r & 63;
    const float* src = (s < 6) ? (l1w + s * 4096) : (s < 12 ? l2w + (s - 6) * 4096 : l3w + (s - 12) * 4096);
    wT[idx] = __float2half(src[k * 64 + c]);
}

// ---------------- agg: one wave per dst; 2 edges per wave-instruction.
// lanes 0-31 -> even edge (2 features/lane), lanes 32-63 -> odd edge.
// Per edge: ONE x dword load + ONE tab dwordx2 load. Meta via wave-private LDS broadcast.
#define PROCP(P, AC0, AC1) { \
    unsigned long long m_ = msl[((P) << 1) + half]; \
    unsigned int mx_ = (unsigned int)m_; \
    unsigned int my_ = (unsigned int)(m_ >> 32); \
    unsigned int xv_ = *(const unsigned int*)(xg + (mx_ & 0xFFFFFu) + fo); \
    uint2 tv_ = *(const uint2*)(tabu + ((mx_ >> 20) << 6) + fo); \
    h2 tf2_ = __builtin_bit_cast(h2, my_); \
    float w0_ = __builtin_amdgcn_fdot2(__builtin_bit_cast(h2, tv_.x), tf2_, 0.0f, false); \
    float w1_ = __builtin_amdgcn_fdot2(__builtin_bit_cast(h2, tv_.y), tf2_, 0.0f, false); \
    h2 xh_ = __builtin_bit_cast(h2, xv_); \
    (AC0) = fmaf(w0_, (float)xh_.x, (AC0)); \
    (AC1) = fmaf(w1_, (float)xh_.y, (AC1)); }

__global__ __launch_bounds__(256) void k_agg(const __half* __restrict__ x, const __half2* __restrict__ tab2,
                                             const uint2* __restrict__ meta, const int* __restrict__ rowptr,
                                             __half* __restrict__ agg){
    __shared__ unsigned long long mlds[4][64];   // wave-private meta stash
    // XCD partition: (blockIdx&7)<4 -> graph A, else graph G; 1 dst per wave.
    int b    = blockIdx.x;                 // < 8192
    int xcd  = b & 7;
    int slot = b >> 3;
    int g    = xcd >> 2;
    int bi   = (slot << 2) + (xcd & 3);    // [0,4096)
    int wq   = threadIdx.x >> 6;
    int lane = threadIdx.x & 63;
    int nn   = (bi << 2) + wq;             // dst atom within graph
    int half = lane >> 5;                  // 0: even edge, 1: odd edge
    int fo   = (lane & 31) << 1;           // feature offset (2 features per lane)
    const int* rp = rowptr + g * (NATOMS + 1);
    int lo = rp[nn], hi = rp[nn + 1];
    const unsigned long long* mg = (const unsigned long long*)(meta + (size_t)g * NEDGE);
    const unsigned int* tabu = (const unsigned int*)tab2;
    const __half* xg = x + ((size_t)(g ? NATOMS : 0) << 6);
    unsigned long long* msl = mlds[wq];
    float a0 = 0.f, a1 = 0.f, b0 = 0.f, b1 = 0.f;
    for (int eb = lo; eb < hi; eb += 64){
        int cnt = hi - eb; if (cnt > 64) cnt = 64;
        // coalesced 512B meta load, zero-padded (zero meta => tf2=0 => contributes 0, safe addr)
        unsigned long long mv = 0;
        if (eb + lane < hi) mv = __builtin_nontemporal_load(&mg[eb + lane]);
        msl[lane] = mv;
        int np = (cnt + 1) >> 1;           // pairs
        int p = 0;
        for (; p + 4 <= np; p += 4){
            PROCP(p + 0, a0, a1);
            PROCP(p + 1, b0, b1);
            PROCP(p + 2, a0, a1);
            PROCP(p + 3, b0, b1);
        }
        for (; p < np; p++){
            PROCP(p, a0, a1);
        }
    }
    a0 += b0; a1 += b1;
    // fold odd-edge partials (lanes 32-63) into lanes 0-31
    a0 += __shfl_xor(a0, 32, 64);
    a1 += __shfl_xor(a1, 32, 64);
    if (lane < 32){
        h2 o; o.x = (_Float16)a0; o.y = (_Float16)a1;
        *(unsigned int*)&agg[((size_t)(g * NATOMS + nn) << 6) + fo] = __builtin_bit_cast(unsigned int, o);
    }
}

// ---------------- MFMA node GEMMs. mode 1: h += ssp(agg@w2+b2)@w3+b3; x = h_new@w1n
//                  mode 0: x = h @ w1n  (lin1).  Weights pre-transposed fp16 (wT).
__global__ __launch_bounds__(256) void k_updlin(const __half* __restrict__ agg, const __half* __restrict__ w2t,
                                                const float* __restrict__ b2, const __half* __restrict__ w3t,
                                                const float* __restrict__ b3, const __half* __restrict__ w1nt,
                                                float* __restrict__ h, __half* __restrict__ x,
                                                int mode, int has_x){
    __shared__ _Float16 A_lds[64 * 72];
    __shared__ _Float16 W_lds[64 * 72];
    int t = threadIdx.x;
    int w = t >> 6, lane = t & 63;
    int m = lane & 15, kg = lane >> 4;
    size_t base = (size_t)blockIdx.x * 64;

#define STAGE_W(SRC) { \
    const unsigned int* wu_ = (const unsigned int*)(SRC); \
    _Pragma("unroll") \
    for (int j = 0; j < 8; j++){ \
        int idx = j * 256 + t; \
        int row = idx >> 5, cu = idx & 31; \
        *(unsigned int*)&W_lds[row * 72 + cu * 2] = wu_[idx]; \
    } }

    // stage A
    if (mode == 1){
        const unsigned int* ag = (const unsigned int*)(agg + base * 64);
        #pragma unroll
        for (int j = 0; j < 8; j++){
            int idx = j * 256 + t;              // < 2048 u32
            int row = idx >> 5, cu = idx & 31;
            *(unsigned int*)&A_lds[row * 72 + cu * 2] = ag[idx];
        }
        STAGE_W(w2t);
    } else {
        #pragma unroll
        for (int j = 0; j < 16; j++){
            int idx = j * 256 + t;              // < 4096
            A_lds[(idx >> 6) * 72 + (idx & 63)] = (_Float16)h[base * 64 + idx];
        }
        STAGE_W(w1nt);
    }
    __syncthreads();

    int arow = (w << 4) + m;
    f32x4 acc[4];

#define GEMM_4CB() { \
    acc[0] = (f32x4)0.f; acc[1] = (f32x4)0.f; acc[2] = (f32x4)0.f; acc[3] = (f32x4)0.f; \
    _Pragma("unroll") \
    for (int kh = 0; kh < 2; kh++){ \
        f16x8 av = *(const f16x8*)&A_lds[arow * 72 + kh * 32 + kg * 8]; \
        _Pragma("unroll") \
        for (int cb = 0; cb < 4; cb++){ \
            f16x8 bv = *(const f16x8*)&W_lds[((cb << 4) + m) * 72 + kh * 32 + kg * 8]; \
            acc[cb] = __builtin_amdgcn_mfma_f32_16x16x32_f16(av, bv, acc[cb], 0, 0, 0); \
        } \
    } }

    if (mode == 0){
        GEMM_4CB();
        #pragma unroll
        for (int cb = 0; cb < 4; cb++){
            int col = (cb << 4) + m;
            #pragma unroll
            for (int v = 0; v < 4; v++){
                int row = (w << 4) + (kg << 2) + v;
                x[(base + row) * 64 + col] = __float2half(acc[cb][v]);
            }
        }
        return;
    }

    // GEMM1: t = ssp(agg @ w2 + b2)  -> A_lds
    GEMM_4CB();
    #pragma unroll
    for (int cb = 0; cb < 4; cb++){
        int col = (cb << 4) + m;
        float bv = b2[col];
        #pragma unroll
        for (int v = 0; v < 4; v++){
            int row = (w << 4) + (kg << 2) + v;
            A_lds[row * 72 + col] = (_Float16)sspf(acc[cb][v] + bv);
        }
    }
    __syncthreads();
    STAGE_W(w3t);
    __syncthreads();

    // GEMM2: h_new = t @ w3 + b3 + h  (global h update; h_new -> A_lds)
    GEMM_4CB();
    #pragma unroll
    for (int cb = 0; cb < 4; cb++){
        int col = (cb << 4) + m;
        float bv = b3[col];
        #pragma unroll
        for (int v = 0; v < 4; v++){
            int row = (w << 4) + (kg << 2) + v;
            size_t o = (base + row) * 64 + col;
            float hv = h[o] + acc[cb][v] + bv;
            h[o] = hv;
            A_lds[row * 72 + col] = (_Float16)hv;
        }
    }
    if (!has_x) return;
    __syncthreads();
    STAGE_W(w1nt);
    __syncthreads();

    // GEMM3: x = h_new @ w1_next  (fp16 out)
    GEMM_4CB();
    #pragma unroll
    for (int cb = 0; cb < 4; cb++){
        int col = (cb << 4) + m;
        #pragma unroll
        for (int v = 0; v < 4; v++){
            int row = (w << 4) + (kg << 2) + v;
            x[(base + row) * 64 + col] = __float2half(acc[cb][v]);
        }
    }
#undef GEMM_4CB
#undef STAGE_W
}

// ---------------- readout: eout[g][f] = sum_n h[n][f]
__global__ __launch_bounds__(256) void k_readout(const float* __restrict__ h, float* __restrict__ eout){
    int f  = threadIdx.x & 63;
    int wq = threadIdx.x >> 6;
    int nodeBase = blockIdx.x * 256 + wq * 64;
    float acc = 0.f;
    #pragma unroll 4
    for (int j = 0; j < 64; j++) acc += h[(size_t)(nodeBase + j) * 64 + f];
    int g = nodeBase >= NATOMS;
    atomicAdd(&eout[g * 64 + f], acc);
}

// ---------------- head: fc1 -> PReLU -> fc2 -> exp
__global__ __launch_bounds__(64) void k_final(const float* __restrict__ eout, const float* __restrict__ addf,
                                              const float* __restrict__ fc1w, const float* __restrict__ fc1b,
                                              const float* __restrict__ pra, const float* __restrict__ fc2w,
                                              const float* __restrict__ fc2b, float* __restrict__ out){
    int f = threadIdx.x;
    float xv = fc1b[f];
    const float inv = 1.0f / 256.0f;
    for (int k = 0; k < 64; k++)  xv = fmaf(eout[k] * inv,      fc1w[k * 64 + f],        xv);
    for (int k = 0; k < 64; k++)  xv = fmaf(eout[64 + k] * inv, fc1w[(64 + k) * 64 + f], xv);
    xv = fmaf(addf[0], fc1w[128 * 64 + f], xv);
    xv = fmaf(addf[1], fc1w[129 * 64 + f], xv);
    float a = pra[0];
    xv = (xv >= 0.f) ? xv : a * xv;
    float s = xv * fc2w[f];
    #pragma unroll
    for (int m = 32; m >= 1; m >>= 1) s += __shfl_xor(s, m, 64);
    if (f == 0) out[0] = expf(s + fc2b[0]);
}

extern "C" void kernel_launch(void* const* d_in, const int* in_sizes, int n_in,
                              void* d_out, int out_size, void* d_ws, size_t ws_size,
                              hipStream_t stream){
    const int*   zA    = (const int*)  d_in[0];
    const float* posA  = (const float*)d_in[1];
    const int*   edgeA = (const int*)  d_in[3];
    const int*   zG    = (const int*)  d_in[4];
    const float* posG  = (const float*)d_in[5];
    const int*   edgeG = (const int*)  d_in[7];
    const float* addf  = (const float*)d_in[8];
    const float* emb   = (const float*)d_in[9];
    const float* mw1   = (const float*)d_in[10];
    const float* mb1   = (const float*)d_in[11];
    const float* mw2   = (const float*)d_in[12];
    const float* mb2   = (const float*)d_in[13];
    const float* l1w   = (const float*)d_in[14];
    const float* l2w   = (const float*)d_in[15];
    const float* l2b   = (const float*)d_in[16];
    const float* l3w   = (const float*)d_in[17];
    const float* l3b   = (const float*)d_in[18];
    const float* fc1w  = (const float*)d_in[19];
    const float* fc1b  = (const float*)d_in[20];
    const float* pra   = (const float*)d_in[21];
    const float* fc2w  = (const float*)d_in[22];
    const float* fc2b  = (const float*)d_in[23];
    float* out = (float*)d_out;

    // workspace layout (~42 MB)
    char* p = (char*)d_ws;
    auto alloc = [&](size_t bytes)->char*{ char* r = p; p += (bytes + 255) & ~(size_t)255; return r; };
    float*   tabf   = (float*)  alloc((size_t)NINT * TK * 64 * 4);   // 3.1 MB
    __half2* tab2   = (__half2*)alloc((size_t)NINT * TK * 64 * 4);   // 3.1 MB
    uint2*   meta8  = (uint2*)  alloc((size_t)2 * NEDGE * 8);        // 8.4 MB
    uint2*   metaF  = (uint2*)  alloc((size_t)2 * NEDGE * 8);        // 8.4 MB
    int*     rowptr = (int*)    alloc((size_t)2 * (NATOMS + 1) * 4);
    int*     gcur   = (int*)    alloc((size_t)2 * NBUCK * 4);
    int*     bhist  = (int*)    alloc((size_t)2 * NBUCK * 4);
    int*     bstart = (int*)    alloc((size_t)2 * (NBUCK + 1) * 4);
    float*   h      = (float*)  alloc((size_t)2 * NATOMS * 64 * 4);  // 8.4 MB
    __half*  x      = (__half*) alloc((size_t)2 * NATOMS * 64 * 2);  // 4.2 MB
    __half*  agg    = (__half*) alloc((size_t)2 * NATOMS * 64 * 2);  // 4.2 MB
    __half*  wT     = (__half*) alloc((size_t)18 * 4096 * 2);        // 147 KB
    float*   eout   = (float*)  alloc(128 * 4);

    hipMemsetAsync(bhist, 0, (size_t)2 * NBUCK * 4, stream);
    hipMemsetAsync(eout, 0, 128 * 4, stream);

    k_embed <<<(2 * NATOMS * 64) / 256, 256, 0, stream>>>(zA, zG, emb, h);
    k_bhist <<<256, 256, 0, stream>>>(edgeA, edgeG, bhist);
    k_bscan <<<2, 512, 0, stream>>>(bhist, bstart, gcur);
    k_place1<<<256,  256, 0, stream>>>(edgeA, edgeG, posA, posG, gcur, meta8);
    k_place2<<<1024, 256, 0, stream>>>(meta8, bstart, rowptr, metaF);
    k_tables<<<(NINT * TK) / 4,        256, 0, stream>>>(mw1, mb1, mw2, mb2, tabf);
    k_pack  <<<(NINT * TK * 64) / 256, 256, 0, stream>>>(tabf, tab2);
    k_wpack <<<(18 * 4096) / 256,      256, 0, stream>>>(l1w, l2w, l3w, wT);

    const __half* w1t0 = wT;
    // lin1 (mode 0)
    k_updlin<<<(2 * NATOMS) / 64, 256, 0, stream>>>(agg, wT, l2b, wT, l3b, w1t0, h, x, 0, 1);
    for (int i = 0; i < NINT; i++){
        k_agg<<<(2 * NATOMS) / 4, 256, 0, stream>>>(x, tab2 + (size_t)i * TK * 64, metaF, rowptr, agg);
        int has_x = (i < NINT - 1);
        const __half* w2t  = wT + (size_t)(6 + i) * 4096;
        const __half* w3t  = wT + (size_t)(12 + i) * 4096;
        const __half* w1nt = wT + (size_t)(has_x ? (i + 1) : 0) * 4096;
        k_updlin<<<(2 * NATOMS) / 64, 256, 0, stream>>>(agg, w2t, l2b + i * 64,
                                                        w3t, l3b + i * 64, w1nt, h, x, 1, has_x);
    }

    k_readout<<<(2 * NATOMS) / 256, 256, 0, stream>>>(h, eout);
    k_final  <<<1, 64, 0, stream>>>(eout, addf, fc1w, fc1b, pra, fc2w, fc2b, out);
}

// Round 12
// 439.956 us; speedup vs baseline: 1.0036x; 1.0036x over previous
//
#include <hip/hip_runtime.h>
#include <hip/hip_bf16.h>
#include <hip/hip_fp16.h>
#include <math.h>

#define NATOMS 16384
#define NEDGE  524288
#define NINT   6
#define NGAUSS 50
#define TK     2048
#define INV_DT 128.0f    // knots at d = k/128, range [0,16)
#define DT     (1.0f/128.0f)
#define LOG2F_ 0.69314718055994530942f
#define NBUCK  512       // per graph, 32 dst atoms each

typedef _Float16 h2    __attribute__((ext_vector_type(2)));
typedef _Float16 f16x8 __attribute__((ext_vector_type(8)));
typedef float    f32x4 __attribute__((ext_vector_type(4)));

__device__ __forceinline__ float sspf(float v){
    return fmaxf(v, 0.f) + log1pf(__expf(-fabsf(v))) - LOG2F_;
}

// ---------------- h = emb[z]  (fp16; rows 0..N-1 = A, N..2N-1 = G)
__global__ __launch_bounds__(256) void k_embed(const int* __restrict__ zA, const int* __restrict__ zG,
                                               const float* __restrict__ emb, __half* __restrict__ h){
    int idx = blockIdx.x * 256 + threadIdx.x;        // < 2*NATOMS*32
    int n = idx >> 5, fp = (idx & 31) << 1;
    int z = (n < NATOMS) ? zA[n] : zG[n - NATOMS];
    float2 e = *(const float2*)&emb[(z << 6) + fp];
    h2 o; o.x = (_Float16)e.x; o.y = (_Float16)e.y;
    *(unsigned int*)&h[(size_t)n * 64 + fp] = __builtin_bit_cast(unsigned int, o);
}

// ---------------- bucket histogram (LDS-privatized, coalesced global adds)
__global__ __launch_bounds__(256) void k_bhist(const int* __restrict__ edgeA, const int* __restrict__ edgeG,
                                               int* __restrict__ bhist){
    __shared__ int lh[NBUCK];
    int blk = blockIdx.x;                    // 256: 0-127 graph A, 128-255 graph G
    int g   = blk >> 7;
    int e0  = (blk & 127) * 4096;
    const int* dst = (g ? edgeG : edgeA) + NEDGE;
    int t = threadIdx.x;
    lh[t] = 0; lh[t + 256] = 0;
    __syncthreads();
    #pragma unroll
    for (int j = 0; j < 16; j++){
        int d = dst[e0 + j * 256 + t];
        atomicAdd(&lh[d >> 5], 1);
    }
    __syncthreads();
    atomicAdd(&bhist[g * NBUCK + t],       lh[t]);
    atomicAdd(&bhist[g * NBUCK + 256 + t], lh[t + 256]);
}

// ---------------- bucket exclusive scan -> bstart (513/graph) + gcur init
__global__ __launch_bounds__(512) void k_bscan(const int* __restrict__ bhist, int* __restrict__ bstart,
                                               int* __restrict__ gcur){
    int g = blockIdx.x;
    __shared__ int s[NBUCK];
    int t = threadIdx.x;
    int v = bhist[g * NBUCK + t];
    s[t] = v;
    __syncthreads();
    for (int off = 1; off < NBUCK; off <<= 1){
        int a = (t >= off) ? s[t - off] : 0;
        __syncthreads();
        s[t] += a;
        __syncthreads();
    }
    int ex = s[t] - v;
    bstart[g * (NBUCK + 1) + t] = ex;
    gcur[g * NBUCK + t] = ex;
    if (t == NBUCK - 1) bstart[g * (NBUCK + 1) + NBUCK] = s[NBUCK - 1];
}

// ---------------- pass 1: bucket-binned placement (coherent writes)
__global__ __launch_bounds__(256) void k_place1(const int* __restrict__ edgeA, const int* __restrict__ edgeG,
                                                const float* __restrict__ posA, const float* __restrict__ posG,
                                                int* __restrict__ gcur, uint2* __restrict__ meta8){
    __shared__ unsigned int lhist[NBUCK];
    __shared__ unsigned int lbase[NBUCK];
    int blk = blockIdx.x;
    int g   = blk >> 7;
    int el0 = (blk & 127) * 4096;
    const int* edge = g ? edgeG : edgeA;
    const float* pos = g ? posG : posA;
    int t = threadIdx.x;
    lhist[t] = 0; lhist[t + 256] = 0;
    __syncthreads();
    unsigned int  mx[16]; float my[16];
    unsigned short rk[16]; unsigned short bb[16];
    #pragma unroll
    for (int j = 0; j < 16; j++){
        int el = el0 + j * 256 + t;
        int src = edge[el], dst = edge[NEDGE + el];
        float dx = pos[src*3+0] - pos[dst*3+0];
        float dy = pos[src*3+1] - pos[dst*3+1];
        float dz = pos[src*3+2] - pos[dst*3+2];
        float d  = sqrtf(fmaf(dx,dx, fmaf(dy,dy, fmaf(dz,dz, 1e-12f))));
        float tp = d * INV_DT;
        int   ti = (int)tp; if (ti > TK - 2) ti = TK - 2;
        float tf = tp - (float)ti;
        int b = dst >> 5;
        bb[j] = (unsigned short)b;
        rk[j] = (unsigned short)atomicAdd(&lhist[b], 1u);
        mx[j] = (unsigned int)src | ((unsigned int)ti << 14) | ((unsigned int)(dst & 31) << 25);
        my[j] = tf;
    }
    __syncthreads();
    lbase[t]       = (unsigned int)atomicAdd(&gcur[g * NBUCK + t],       (int)lhist[t]);
    lbase[t + 256] = (unsigned int)atomicAdd(&gcur[g * NBUCK + t + 256], (int)lhist[t + 256]);
    __syncthreads();
    #pragma unroll
    for (int j = 0; j < 16; j++){
        unsigned int pos_ = lbase[bb[j]] + rk[j];
        meta8[(size_t)g * NEDGE + pos_] = make_uint2(mx[j], __float_as_uint(my[j]));
    }
}

// ---------------- pass 2: per-bucket rowptr build + per-dst scatter (L2-hot)
// metaF: m.x = srcElem(20 = src<<6) | ti<<20(11) ; m.y = half2(1-tf, tf)
__global__ __launch_bounds__(256) void k_place2(const uint2* __restrict__ meta8, const int* __restrict__ bstart,
                                                int* __restrict__ rowptr, uint2* __restrict__ metaF){
    __shared__ int lcnt[32];
    __shared__ int lcur[32];
    int blk = blockIdx.x;
    int g = blk >> 9;
    int b = blk & (NBUCK - 1);
    int lo = bstart[g * (NBUCK + 1) + b];
    int hi = bstart[g * (NBUCK + 1) + b + 1];
    int t = threadIdx.x;
    if (t < 32) lcnt[t] = 0;
    __syncthreads();
    for (int idx = lo + t; idx < hi; idx += 256){
        uint2 m = meta8[(size_t)g * NEDGE + idx];
        atomicAdd(&lcnt[(m.x >> 25) & 31u], 1);
    }
    __syncthreads();
    if (t == 0){
        int run = lo;
        int* rp = rowptr + g * (NATOMS + 1) + (b << 5);
        #pragma unroll
        for (int i = 0; i < 32; i++){
            int c = lcnt[i];
            lcur[i] = run;
            rp[i] = run;
            run += c;
        }
        if (b == NBUCK - 1) rowptr[g * (NATOMS + 1) + NATOMS] = hi;
    }
    __syncthreads();
    for (int idx = lo + t; idx < hi; idx += 256){
        uint2 m = meta8[(size_t)g * NEDGE + idx];
        int dl = (int)((m.x >> 25) & 31u);
        int p = atomicAdd(&lcur[dl], 1);
        float tf = __uint_as_float(m.y);
        h2 t2; t2.x = (_Float16)(1.0f - tf); t2.y = (_Float16)tf;
        unsigned int src = m.x & 16383u;
        unsigned int ti  = (m.x >> 14) & 2047u;
        metaF[(size_t)g * NEDGE + p] = make_uint2((src << 6) | (ti << 20),
                                                  __builtin_bit_cast(unsigned int, t2));
    }
}

// ---------------- tabulate W_i(d)*C(d) on TK knots (fp32 scratch)
__global__ __launch_bounds__(256) void k_tables(const float* __restrict__ mw1, const float* __restrict__ mb1,
                                                const float* __restrict__ mw2, const float* __restrict__ mb2,
                                                float* __restrict__ tabf){
    int wv   = blockIdx.x * 4 + (threadIdx.x >> 6);
    int lane = threadIdx.x & 63;
    int i = wv >> 11, k = wv & (TK - 1);
    float d = (float)k * DT;
    const float step  = 10.0f / 49.0f;
    const float coeff = -0.5f / (step * step);
    float u = mb1[(i << 6) + lane];
    #pragma unroll
    for (int gg = 0; gg < NGAUSS; gg++){
        float od = d - (float)gg * step;
        float ea = __expf(coeff * od * od);
        u = fmaf(ea, mw1[((i * NGAUSS + gg) << 6) + lane], u);
    }
    float t = sspf(u);
    float w = mb2[(i << 6) + lane];
    #pragma unroll
    for (int gg = 0; gg < 64; gg++){
        float tg = __shfl(t, gg, 64);
        w = fmaf(tg, mw2[(((i << 6) + gg) << 6) + lane], w);
    }
    float cc = 0.5f * (__cosf(d * 0.31415926535897932f) + 1.0f);
    tabf[((size_t)(i * TK + k) << 6) + lane] = w * cc;
}

// ---------------- pack interleaved half2 table: tab2[k][lane] = (Wk, Wk+1)
__global__ __launch_bounds__(256) void k_pack(const float* __restrict__ tabf, __half2* __restrict__ tab2){
    size_t idx = (size_t)blockIdx.x * 256 + threadIdx.x;
    size_t rem = idx & ((size_t)TK * 64 - 1);
    float a = tabf[idx];
    float b = (rem < (size_t)TK * 64 - 64) ? tabf[idx + 64] : a;
    tab2[idx] = __floats2half2_rn(a, b);
}

// ---------------- pack 18 weight matrices transposed to fp16: wT[s][c][k] = w_s[k][c]
__global__ __launch_bounds__(256) void k_wpack(const float* __restrict__ l1w, const float* __restrict__ l2w,
                                               const float* __restrict__ l3w, __half* __restrict__ wT){
    int idx = blockIdx.x * 256 + threadIdx.x;   // < 18*4096
    int s = idx >> 12;
    int r = idx & 4095;
    int c = r >> 6, k = r & 63;
    const float* src = (s < 6) ? (l1w + s * 4096) : (s < 12 ? l2w + (s - 6) * 4096 : l3w + (s - 12) * 4096);
    wT[idx] = __float2half(src[k * 64 + c]);
}

// ---------------- agg: one wave per dst; 2 edges per wave-instruction (lanes split 32/32)
#define PROCP(P, AC0, AC1) { \
    unsigned long long m_ = msl[((P) << 1) + half]; \
    unsigned int mx_ = (unsigned int)m_; \
    unsigned int my_ = (unsigned int)(m_ >> 32); \
    unsigned int xv_ = *(const unsigned int*)(xg + (mx_ & 0xFFFFFu) + fo); \
    uint2 tv_ = *(const uint2*)(tabu + ((mx_ >> 20) << 6) + fo); \
    h2 tf2_ = __builtin_bit_cast(h2, my_); \
    float w0_ = __builtin_amdgcn_fdot2(__builtin_bit_cast(h2, tv_.x), tf2_, 0.0f, false); \
    float w1_ = __builtin_amdgcn_fdot2(__builtin_bit_cast(h2, tv_.y), tf2_, 0.0f, false); \
    h2 xh_ = __builtin_bit_cast(h2, xv_); \
    (AC0) = fmaf(w0_, (float)xh_.x, (AC0)); \
    (AC1) = fmaf(w1_, (float)xh_.y, (AC1)); }

__global__ __launch_bounds__(256) void k_agg(const __half* __restrict__ x, const __half2* __restrict__ tab2,
                                             const uint2* __restrict__ meta, const int* __restrict__ rowptr,
                                             __half* __restrict__ agg){
    __shared__ unsigned long long mlds[4][64];   // wave-private meta stash
    int b    = blockIdx.x;                 // < 8192
    int xcd  = b & 7;
    int slot = b >> 3;
    int g    = xcd >> 2;
    int bi   = (slot << 2) + (xcd & 3);    // [0,4096)
    int wq   = threadIdx.x >> 6;
    int lane = threadIdx.x & 63;
    int nn   = (bi << 2) + wq;             // dst atom within graph
    int half = lane >> 5;                  // 0: even edge, 1: odd edge
    int fo   = (lane & 31) << 1;           // feature offset (2 per lane)
    const int* rp = rowptr + g * (NATOMS + 1);
    int lo = rp[nn], hi = rp[nn + 1];
    const unsigned long long* mg = (const unsigned long long*)(meta + (size_t)g * NEDGE);
    const unsigned int* tabu = (const unsigned int*)tab2;
    const __half* xg = x + ((size_t)(g ? NATOMS : 0) << 6);
    unsigned long long* msl = mlds[wq];
    float a0 = 0.f, a1 = 0.f, b0 = 0.f, b1 = 0.f;
    for (int eb = lo; eb < hi; eb += 64){
        int cnt = hi - eb; if (cnt > 64) cnt = 64;
        unsigned long long mv = 0;
        if (eb + lane < hi) mv = __builtin_nontemporal_load(&mg[eb + lane]);
        msl[lane] = mv;
        int np = (cnt + 1) >> 1;
        int p = 0;
        for (; p + 4 <= np; p += 4){
            PROCP(p + 0, a0, a1);
            PROCP(p + 1, b0, b1);
            PROCP(p + 2, a0, a1);
            PROCP(p + 3, b0, b1);
        }
        for (; p < np; p++){
            PROCP(p, a0, a1);
        }
    }
    a0 += b0; a1 += b1;
    a0 += __shfl_xor(a0, 32, 64);
    a1 += __shfl_xor(a1, 32, 64);
    if (lane < 32){
        h2 o; o.x = (_Float16)a0; o.y = (_Float16)a1;
        *(unsigned int*)&agg[((size_t)(g * NATOMS + nn) << 6) + fo] = __builtin_bit_cast(unsigned int, o);
    }
}

// ---------------- barrier-free MFMA node GEMMs (wave-private 16-row tiles).
// mode 1: h += ssp(agg@w2+b2)@w3+b3 ; x = h_new @ w1n.   mode 0: x = h @ w1n.
// B-frags straight from L2-hot wT (global); chaining via wave-private LDS tile; no __syncthreads.
__global__ __launch_bounds__(256) void k_updlin(const __half* __restrict__ agg, const __half* __restrict__ w2t,
                                                const float* __restrict__ b2, const __half* __restrict__ w3t,
                                                const float* __restrict__ b3, const __half* __restrict__ w1nt,
                                                __half* __restrict__ h, __half* __restrict__ x,
                                                int mode, int has_x){
    __shared__ _Float16 T[4][16 * 72];      // per-wave 16x64 tile, stride 72 (16B-aligned rows)
    int t = threadIdx.x;
    int w = t >> 6, lane = t & 63;
    int m = lane & 15, kg = lane >> 4;
    size_t base = (size_t)blockIdx.x * 64 + ((size_t)w << 4);   // global node row of this wave's tile
    _Float16* Tw = T[w];
    int lr = lane >> 2, lc = (lane & 3) << 4;    // linear chunk: row lr, cols lc..lc+15

    const _Float16* aggh = (const _Float16*)agg;
    const _Float16* w2h  = (const _Float16*)w2t;
    const _Float16* w3h  = (const _Float16*)w3t;
    const _Float16* w1h  = (const _Float16*)w1nt;
    _Float16* hh = (_Float16*)h;
    _Float16* xh = (_Float16*)x;

    f32x4 acc[4];

#define GEMM_GLOBAL_A(AP, WT) { \
    acc[0] = (f32x4)0.f; acc[1] = (f32x4)0.f; acc[2] = (f32x4)0.f; acc[3] = (f32x4)0.f; \
    _Pragma("unroll") \
    for (int kh = 0; kh < 2; kh++){ \
        f16x8 av = *(const f16x8*)&(AP)[((size_t)m << 6) + kh * 32 + kg * 8]; \
        _Pragma("unroll") \
        for (int cb = 0; cb < 4; cb++){ \
            f16x8 bv = *(const f16x8*)&(WT)[(size_t)((cb << 4) + m) * 64 + kh * 32 + kg * 8]; \
            acc[cb] = __builtin_amdgcn_mfma_f32_16x16x32_f16(av, bv, acc[cb], 0, 0, 0); \
        } \
    } }

#define GEMM_LDS_A(WT) { \
    acc[0] = (f32x4)0.f; acc[1] = (f32x4)0.f; acc[2] = (f32x4)0.f; acc[3] = (f32x4)0.f; \
    _Pragma("unroll") \
    for (int kh = 0; kh < 2; kh++){ \
        f16x8 av = *(const f16x8*)&Tw[m * 72 + kh * 32 + kg * 8]; \
        _Pragma("unroll") \
        for (int cb = 0; cb < 4; cb++){ \
            f16x8 bv = *(const f16x8*)&(WT)[(size_t)((cb << 4) + m) * 64 + kh * 32 + kg * 8]; \
            acc[cb] = __builtin_amdgcn_mfma_f32_16x16x32_f16(av, bv, acc[cb], 0, 0, 0); \
        } \
    } }

#define SCATTER_RAW() { \
    _Pragma("unroll") \
    for (int cb = 0; cb < 4; cb++){ \
        _Pragma("unroll") \
        for (int v = 0; v < 4; v++) \
            Tw[((kg << 2) + v) * 72 + (cb << 4) + m] = (_Float16)acc[cb][v]; \
    } }

    if (mode == 0){
        GEMM_GLOBAL_A(hh + base * 64, w1h);
        SCATTER_RAW();
        f16x8 c0 = *(const f16x8*)&Tw[lr * 72 + lc];
        f16x8 c1 = *(const f16x8*)&Tw[lr * 72 + lc + 8];
        *(f16x8*)&xh[(base + lr) * 64 + lc]     = c0;
        *(f16x8*)&xh[(base + lr) * 64 + lc + 8] = c1;
        return;
    }

    // GEMM1: t = ssp(agg @ w2 + b2) -> Tw (scatter with op)
    GEMM_GLOBAL_A(aggh + base * 64, w2h);
    #pragma unroll
    for (int cb = 0; cb < 4; cb++){
        float bv = b2[(cb << 4) + m];
        #pragma unroll
        for (int v = 0; v < 4; v++)
            Tw[((kg << 2) + v) * 72 + (cb << 4) + m] = (_Float16)sspf(acc[cb][v] + bv);
    }

    // GEMM2: C = t @ w3 ; h_new = C + b3 + h_old (coalesced via linear chunks)
    GEMM_LDS_A(w3h);
    SCATTER_RAW();
    {
        f16x8 c0 = *(const f16x8*)&Tw[lr * 72 + lc];
        f16x8 c1 = *(const f16x8*)&Tw[lr * 72 + lc + 8];
        float bb[16];
        *(float4*)&bb[0]  = *(const float4*)&b3[lc];
        *(float4*)&bb[4]  = *(const float4*)&b3[lc + 4];
        *(float4*)&bb[8]  = *(const float4*)&b3[lc + 8];
        *(float4*)&bb[12] = *(const float4*)&b3[lc + 12];
        f16x8 h0 = *(const f16x8*)&hh[(base + lr) * 64 + lc];
        f16x8 h1 = *(const f16x8*)&hh[(base + lr) * 64 + lc + 8];
        f16x8 n0, n1;
        #pragma unroll
        for (int j = 0; j < 8; j++){
            n0[j] = (_Float16)((float)c0[j] + bb[j]     + (float)h0[j]);
            n1[j] = (_Float16)((float)c1[j] + bb[8 + j] + (float)h1[j]);
        }
        *(f16x8*)&hh[(base + lr) * 64 + lc]     = n0;
        *(f16x8*)&hh[(base + lr) * 64 + lc + 8] = n1;
        *(f16x8*)&Tw[lr * 72 + lc]     = n0;
        *(f16x8*)&Tw[lr * 72 + lc + 8] = n1;
    }
    if (!has_x) return;

    // GEMM3: x = h_new @ w1_next
    GEMM_LDS_A(w1h);
    SCATTER_RAW();
    {
        f16x8 c0 = *(const f16x8*)&Tw[lr * 72 + lc];
        f16x8 c1 = *(const f16x8*)&Tw[lr * 72 + lc + 8];
        *(f16x8*)&xh[(base + lr) * 64 + lc]     = c0;
        *(f16x8*)&xh[(base + lr) * 64 + lc + 8] = c1;
    }
#undef GEMM_GLOBAL_A
#undef GEMM_LDS_A
#undef SCATTER_RAW
}

// ---------------- readout: eout[g][f] = sum_n h[n][f]  (h fp16)
__global__ __launch_bounds__(256) void k_readout(const __half* __restrict__ h, float* __restrict__ eout){
    int f  = threadIdx.x & 63;
    int wq = threadIdx.x >> 6;
    int nodeBase = blockIdx.x * 256 + wq * 64;
    float acc = 0.f;
    #pragma unroll 4
    for (int j = 0; j < 64; j++) acc += __half2float(h[(size_t)(nodeBase + j) * 64 + f]);
    int g = nodeBase >= NATOMS;
    atomicAdd(&eout[g * 64 + f], acc);
}

// ---------------- head: fc1 -> PReLU -> fc2 -> exp
__global__ __launch_bounds__(64) void k_final(const float* __restrict__ eout, const float* __restrict__ addf,
                                              const float* __restrict__ fc1w, const float* __restrict__ fc1b,
                                              const float* __restrict__ pra, const float* __restrict__ fc2w,
                                              const float* __restrict__ fc2b, float* __restrict__ out){
    int f = threadIdx.x;
    float xv = fc1b[f];
    const float inv = 1.0f / 256.0f;
    for (int k = 0; k < 64; k++)  xv = fmaf(eout[k] * inv,      fc1w[k * 64 + f],        xv);
    for (int k = 0; k < 64; k++)  xv = fmaf(eout[64 + k] * inv, fc1w[(64 + k) * 64 + f], xv);
    xv = fmaf(addf[0], fc1w[128 * 64 + f], xv);
    xv = fmaf(addf[1], fc1w[129 * 64 + f], xv);
    float a = pra[0];
    xv = (xv >= 0.f) ? xv : a * xv;
    float s = xv * fc2w[f];
    #pragma unroll
    for (int m = 32; m >= 1; m >>= 1) s += __shfl_xor(s, m, 64);
    if (f == 0) out[0] = expf(s + fc2b[0]);
}

extern "C" void kernel_launch(void* const* d_in, const int* in_sizes, int n_in,
                              void* d_out, int out_size, void* d_ws, size_t ws_size,
                              hipStream_t stream){
    const int*   zA    = (const int*)  d_in[0];
    const float* posA  = (const float*)d_in[1];
    const int*   edgeA = (const int*)  d_in[3];
    const int*   zG    = (const int*)  d_in[4];
    const float* posG  = (const float*)d_in[5];
    const int*   edgeG = (const int*)  d_in[7];
    const float* addf  = (const float*)d_in[8];
    const float* emb   = (const float*)d_in[9];
    const float* mw1   = (const float*)d_in[10];
    const float* mb1   = (const float*)d_in[11];
    const float* mw2   = (const float*)d_in[12];
    const float* mb2   = (const float*)d_in[13];
    const float* l1w   = (const float*)d_in[14];
    const float* l2w   = (const float*)d_in[15];
    const float* l2b   = (const float*)d_in[16];
    const float* l3w   = (const float*)d_in[17];
    const float* l3b   = (const float*)d_in[18];
    const float* fc1w  = (const float*)d_in[19];
    const float* fc1b  = (const float*)d_in[20];
    const float* pra   = (const float*)d_in[21];
    const float* fc2w  = (const float*)d_in[22];
    const float* fc2b  = (const float*)d_in[23];
    float* out = (float*)d_out;

    // workspace layout (~38 MB)
    char* p = (char*)d_ws;
    auto alloc = [&](size_t bytes)->char*{ char* r = p; p += (bytes + 255) & ~(size_t)255; return r; };
    float*   tabf   = (float*)  alloc((size_t)NINT * TK * 64 * 4);   // 3.1 MB
    __half2* tab2   = (__half2*)alloc((size_t)NINT * TK * 64 * 4);   // 3.1 MB
    uint2*   meta8  = (uint2*)  alloc((size_t)2 * NEDGE * 8);        // 8.4 MB
    uint2*   metaF  = (uint2*)  alloc((size_t)2 * NEDGE * 8);        // 8.4 MB
    int*     rowptr = (int*)    alloc((size_t)2 * (NATOMS + 1) * 4);
    int*     gcur   = (int*)    alloc((size_t)2 * NBUCK * 4);
    int*     bhist  = (int*)    alloc((size_t)2 * NBUCK * 4);
    int*     bstart = (int*)    alloc((size_t)2 * (NBUCK + 1) * 4);
    __half*  h      = (__half*) alloc((size_t)2 * NATOMS * 64 * 2);  // 4.2 MB
    __half*  x      = (__half*) alloc((size_t)2 * NATOMS * 64 * 2);  // 4.2 MB
    __half*  agg    = (__half*) alloc((size_t)2 * NATOMS * 64 * 2);  // 4.2 MB
    __half*  wT     = (__half*) alloc((size_t)18 * 4096 * 2);        // 147 KB
    float*   eout   = (float*)  alloc(128 * 4);

    hipMemsetAsync(bhist, 0, (size_t)2 * NBUCK * 4, stream);
    hipMemsetAsync(eout, 0, 128 * 4, stream);

    k_embed <<<(2 * NATOMS * 32) / 256, 256, 0, stream>>>(zA, zG, emb, h);
    k_bhist <<<256, 256, 0, stream>>>(edgeA, edgeG, bhist);
    k_bscan <<<2, 512, 0, stream>>>(bhist, bstart, gcur);
    k_place1<<<256,  256, 0, stream>>>(edgeA, edgeG, posA, posG, gcur, meta8);
    k_place2<<<1024, 256, 0, stream>>>(meta8, bstart, rowptr, metaF);
    k_tables<<<(NINT * TK) / 4,        256, 0, stream>>>(mw1, mb1, mw2, mb2, tabf);
    k_pack  <<<(NINT * TK * 64) / 256, 256, 0, stream>>>(tabf, tab2);
    k_wpack <<<(18 * 4096) / 256,      256, 0, stream>>>(l1w, l2w, l3w, wT);

    const __half* w1t0 = wT;
    // lin1 (mode 0)
    k_updlin<<<(2 * NATOMS) / 64, 256, 0, stream>>>(agg, wT, l2b, wT, l3b, w1t0, h, x, 0, 1);
    for (int i = 0; i < NINT; i++){
        k_agg<<<(2 * NATOMS) / 4, 256, 0, stream>>>(x, tab2 + (size_t)i * TK * 64, metaF, rowptr, agg);
        int has_x = (i < NINT - 1);
        const __half* w2t  = wT + (size_t)(6 + i) * 4096;
        const __half* w3t  = wT + (size_t)(12 + i) * 4096;
        const __half* w1nt = wT + (size_t)(has_x ? (i + 1) : 0) * 4096;
        k_updlin<<<(2 * NATOMS) / 64, 256, 0, stream>>>(agg, w2t, l2b + i * 64,
                                                        w3t, l3b + i * 64, w1nt, h, x, 1, has_x);
    }

    k_readout<<<(2 * NATOMS) / 256, 256, 0, stream>>>(h, eout);
    k_final  <<<1, 64, 0, stream>>>(eout, addf, fc1w, fc1b, pra, fc2w, fc2b, out);
}

// Round 13
// 428.690 us; speedup vs baseline: 1.0300x; 1.0263x over previous
//
#include <hip/hip_runtime.h>
#include <hip/hip_bf16.h>
#include <hip/hip_fp16.h>
#include <math.h>

#define NATOMS 16384
#define NEDGE  524288
#define NINT   6
#define NGAUSS 50
#define TK     1024
#define INV_DT 64.0f     // knots at d = k/64, range [0,16)
#define DT     (1.0f/64.0f)
#define LOG2F_ 0.69314718055994530942f
#define NBUCK  512       // per graph, 32 dst atoms each

typedef _Float16 h2    __attribute__((ext_vector_type(2)));
typedef _Float16 f16x8 __attribute__((ext_vector_type(8)));
typedef float    f32x4 __attribute__((ext_vector_type(4)));

__device__ __forceinline__ float sspf(float v){
    return fmaxf(v, 0.f) + log1pf(__expf(-fabsf(v))) - LOG2F_;
}

// ---------------- h = emb[z]  (fp16; rows 0..N-1 = A, N..2N-1 = G)
__global__ __launch_bounds__(256) void k_embed(const int* __restrict__ zA, const int* __restrict__ zG,
                                               const float* __restrict__ emb, __half* __restrict__ h){
    int idx = blockIdx.x * 256 + threadIdx.x;        // < 2*NATOMS*32
    int n = idx >> 5, fp = (idx & 31) << 1;
    int z = (n < NATOMS) ? zA[n] : zG[n - NATOMS];
    float2 e = *(const float2*)&emb[(z << 6) + fp];
    h2 o; o.x = (_Float16)e.x; o.y = (_Float16)e.y;
    *(unsigned int*)&h[(size_t)n * 64 + fp] = __builtin_bit_cast(unsigned int, o);
}

// ---------------- bucket histogram (LDS-privatized, coalesced global adds)
__global__ __launch_bounds__(256) void k_bhist(const int* __restrict__ edgeA, const int* __restrict__ edgeG,
                                               int* __restrict__ bhist){
    __shared__ int lh[NBUCK];
    int blk = blockIdx.x;                    // 256: 0-127 graph A, 128-255 graph G
    int g   = blk >> 7;
    int e0  = (blk & 127) * 4096;
    const int* dst = (g ? edgeG : edgeA) + NEDGE;
    int t = threadIdx.x;
    lh[t] = 0; lh[t + 256] = 0;
    __syncthreads();
    #pragma unroll
    for (int j = 0; j < 16; j++){
        int d = dst[e0 + j * 256 + t];
        atomicAdd(&lh[d >> 5], 1);
    }
    __syncthreads();
    atomicAdd(&bhist[g * NBUCK + t],       lh[t]);
    atomicAdd(&bhist[g * NBUCK + 256 + t], lh[t + 256]);
}

// ---------------- bucket exclusive scan -> bstart (513/graph) + gcur init
__global__ __launch_bounds__(512) void k_bscan(const int* __restrict__ bhist, int* __restrict__ bstart,
                                               int* __restrict__ gcur){
    int g = blockIdx.x;
    __shared__ int s[NBUCK];
    int t = threadIdx.x;
    int v = bhist[g * NBUCK + t];
    s[t] = v;
    __syncthreads();
    for (int off = 1; off < NBUCK; off <<= 1){
        int a = (t >= off) ? s[t - off] : 0;
        __syncthreads();
        s[t] += a;
        __syncthreads();
    }
    int ex = s[t] - v;
    bstart[g * (NBUCK + 1) + t] = ex;
    gcur[g * NBUCK + t] = ex;
    if (t == NBUCK - 1) bstart[g * (NBUCK + 1) + NBUCK] = s[NBUCK - 1];
}

// ---------------- pass 1: bucket-binned placement (coherent writes)
__global__ __launch_bounds__(256) void k_place1(const int* __restrict__ edgeA, const int* __restrict__ edgeG,
                                                const float* __restrict__ posA, const float* __restrict__ posG,
                                                int* __restrict__ gcur, uint2* __restrict__ meta8){
    __shared__ unsigned int lhist[NBUCK];
    __shared__ unsigned int lbase[NBUCK];
    int blk = blockIdx.x;
    int g   = blk >> 7;
    int el0 = (blk & 127) * 4096;
    const int* edge = g ? edgeG : edgeA;
    const float* pos = g ? posG : posA;
    int t = threadIdx.x;
    lhist[t] = 0; lhist[t + 256] = 0;
    __syncthreads();
    unsigned int  mx[16]; float my[16];
    unsigned short rk[16]; unsigned short bb[16];
    #pragma unroll
    for (int j = 0; j < 16; j++){
        int el = el0 + j * 256 + t;
        int src = edge[el], dst = edge[NEDGE + el];
        float dx = pos[src*3+0] - pos[dst*3+0];
        float dy = pos[src*3+1] - pos[dst*3+1];
        float dz = pos[src*3+2] - pos[dst*3+2];
        float d  = sqrtf(fmaf(dx,dx, fmaf(dy,dy, fmaf(dz,dz, 1e-12f))));
        float tp = d * INV_DT;
        int   ti = (int)tp; if (ti > TK - 2) ti = TK - 2;
        float tf = tp - (float)ti;
        int b = dst >> 5;
        bb[j] = (unsigned short)b;
        rk[j] = (unsigned short)atomicAdd(&lhist[b], 1u);
        mx[j] = (unsigned int)src | ((unsigned int)ti << 14) | ((unsigned int)(dst & 31) << 25);
        my[j] = tf;
    }
    __syncthreads();
    lbase[t]       = (unsigned int)atomicAdd(&gcur[g * NBUCK + t],       (int)lhist[t]);
    lbase[t + 256] = (unsigned int)atomicAdd(&gcur[g * NBUCK + t + 256], (int)lhist[t + 256]);
    __syncthreads();
    #pragma unroll
    for (int j = 0; j < 16; j++){
        unsigned int pos_ = lbase[bb[j]] + rk[j];
        meta8[(size_t)g * NEDGE + pos_] = make_uint2(mx[j], __float_as_uint(my[j]));
    }
}

// ---------------- pass 2: per-bucket rowptr build + per-dst scatter (L2-hot)
// metaF: m.x = srcElem(20 = src<<6) | ti<<20(11) ; m.y = half2(1-tf, tf)
__global__ __launch_bounds__(256) void k_place2(const uint2* __restrict__ meta8, const int* __restrict__ bstart,
                                                int* __restrict__ rowptr, uint2* __restrict__ metaF){
    __shared__ int lcnt[32];
    __shared__ int lcur[32];
    int blk = blockIdx.x;
    int g = blk >> 9;
    int b = blk & (NBUCK - 1);
    int lo = bstart[g * (NBUCK + 1) + b];
    int hi = bstart[g * (NBUCK + 1) + b + 1];
    int t = threadIdx.x;
    if (t < 32) lcnt[t] = 0;
    __syncthreads();
    for (int idx = lo + t; idx < hi; idx += 256){
        uint2 m = meta8[(size_t)g * NEDGE + idx];
        atomicAdd(&lcnt[(m.x >> 25) & 31u], 1);
    }
    __syncthreads();
    if (t == 0){
        int run = lo;
        int* rp = rowptr + g * (NATOMS + 1) + (b << 5);
        #pragma unroll
        for (int i = 0; i < 32; i++){
            int c = lcnt[i];
            lcur[i] = run;
            rp[i] = run;
            run += c;
        }
        if (b == NBUCK - 1) rowptr[g * (NATOMS + 1) + NATOMS] = hi;
    }
    __syncthreads();
    for (int idx = lo + t; idx < hi; idx += 256){
        uint2 m = meta8[(size_t)g * NEDGE + idx];
        int dl = (int)((m.x >> 25) & 31u);
        int p = atomicAdd(&lcur[dl], 1);
        float tf = __uint_as_float(m.y);
        h2 t2; t2.x = (_Float16)(1.0f - tf); t2.y = (_Float16)tf;
        unsigned int src = m.x & 16383u;
        unsigned int ti  = (m.x >> 14) & 2047u;
        metaF[(size_t)g * NEDGE + p] = make_uint2((src << 6) | (ti << 20),
                                                  __builtin_bit_cast(unsigned int, t2));
    }
}

// ---------------- tabulate W_i(d)*C(d) on TK knots (fp32 scratch)
__global__ __launch_bounds__(256) void k_tables(const float* __restrict__ mw1, const float* __restrict__ mb1,
                                                const float* __restrict__ mw2, const float* __restrict__ mb2,
                                                float* __restrict__ tabf){
    int wv   = blockIdx.x * 4 + (threadIdx.x >> 6);  // < NINT*TK
    int lane = threadIdx.x & 63;
    int i = wv >> 10, k = wv & (TK - 1);
    float d = (float)k * DT;
    const float step  = 10.0f / 49.0f;
    const float coeff = -0.5f / (step * step);
    float u = mb1[(i << 6) + lane];
    #pragma unroll
    for (int gg = 0; gg < NGAUSS; gg++){
        float od = d - (float)gg * step;
        float ea = __expf(coeff * od * od);
        u = fmaf(ea, mw1[((i * NGAUSS + gg) << 6) + lane], u);
    }
    float t = sspf(u);
    float w = mb2[(i << 6) + lane];
    #pragma unroll
    for (int gg = 0; gg < 64; gg++){
        float tg = __shfl(t, gg, 64);
        w = fmaf(tg, mw2[(((i << 6) + gg) << 6) + lane], w);
    }
    float cc = 0.5f * (__cosf(d * 0.31415926535897932f) + 1.0f);
    tabf[((size_t)(i * TK + k) << 6) + lane] = w * cc;
}

// ---------------- pack interleaved half2 table: tab2[k][lane] = (Wk, Wk+1)
__global__ __launch_bounds__(256) void k_pack(const float* __restrict__ tabf, __half2* __restrict__ tab2){
    size_t idx = (size_t)blockIdx.x * 256 + threadIdx.x;   // < NINT*TK*64
    size_t rem = idx & ((size_t)TK * 64 - 1);
    float a = tabf[idx];
    float b = (rem < (size_t)TK * 64 - 64) ? tabf[idx + 64] : a;
    tab2[idx] = __floats2half2_rn(a, b);
}

// ---------------- pack 18 weight matrices transposed to fp16: wT[s][c][k] = w_s[k][c]
__global__ __launch_bounds__(256) void k_wpack(const float* __restrict__ l1w, const float* __restrict__ l2w,
                                               const float* __restrict__ l3w, __half* __restrict__ wT){
    int idx = blockIdx.x * 256 + threadIdx.x;   // < 18*4096
    int s = idx >> 12;
    int r = idx & 4095;
    int c = r >> 6, k = r & 63;
    const float* src = (s < 6) ? (l1w + s * 4096) : (s < 12 ? l2w + (s - 6) * 4096 : l3w + (s - 12) * 4096);
    wT[idx] = __float2half(src[k * 64 + c]);
}

// ---------------- agg: one wave per dst; 2 edges per wave-instruction (lanes split 32/32)
// forced 8 waves/SIMD occupancy; 8-pair unroll for 16 outstanding gathers/wave
#define PROCP(P, AC0, AC1) { \
    unsigned long long m_ = msl[((P) << 1) + half]; \
    unsigned int mx_ = (unsigned int)m_; \
    unsigned int my_ = (unsigned int)(m_ >> 32); \
    unsigned int xv_ = *(const unsigned int*)(xg + (mx_ & 0xFFFFFu) + fo); \
    uint2 tv_ = *(const uint2*)(tabu + ((mx_ >> 20) << 6) + fo); \
    h2 tf2_ = __builtin_bit_cast(h2, my_); \
    float w0_ = __builtin_amdgcn_fdot2(__builtin_bit_cast(h2, tv_.x), tf2_, 0.0f, false); \
    float w1_ = __builtin_amdgcn_fdot2(__builtin_bit_cast(h2, tv_.y), tf2_, 0.0f, false); \
    h2 xh_ = __builtin_bit_cast(h2, xv_); \
    (AC0) = fmaf(w0_, (float)xh_.x, (AC0)); \
    (AC1) = fmaf(w1_, (float)xh_.y, (AC1)); }

__global__ __launch_bounds__(256, 8) void k_agg(const __half* __restrict__ x, const __half2* __restrict__ tab2,
                                                const uint2* __restrict__ meta, const int* __restrict__ rowptr,
                                                __half* __restrict__ agg){
    __shared__ unsigned long long mlds[4][64];   // wave-private meta stash
    int b    = blockIdx.x;                 // < 8192
    int xcd  = b & 7;
    int slot = b >> 3;
    int g    = xcd >> 2;
    int bi   = (slot << 2) + (xcd & 3);    // [0,4096)
    int wq   = threadIdx.x >> 6;
    int lane = threadIdx.x & 63;
    int nn   = (bi << 2) + wq;             // dst atom within graph
    int half = lane >> 5;                  // 0: even edge, 1: odd edge
    int fo   = (lane & 31) << 1;           // feature offset (2 per lane)
    const int* rp = rowptr + g * (NATOMS + 1);
    int lo = rp[nn], hi = rp[nn + 1];
    const unsigned long long* mg = (const unsigned long long*)(meta + (size_t)g * NEDGE);
    const unsigned int* tabu = (const unsigned int*)tab2;
    const __half* xg = x + ((size_t)(g ? NATOMS : 0) << 6);
    unsigned long long* msl = mlds[wq];
    float a0 = 0.f, a1 = 0.f, b0 = 0.f, b1 = 0.f;
    for (int eb = lo; eb < hi; eb += 64){
        int cnt = hi - eb; if (cnt > 64) cnt = 64;
        unsigned long long mv = 0;
        if (eb + lane < hi) mv = __builtin_nontemporal_load(&mg[eb + lane]);
        msl[lane] = mv;
        int np = (cnt + 1) >> 1;
        int p = 0;
        for (; p + 8 <= np; p += 8){
            PROCP(p + 0, a0, a1);
            PROCP(p + 1, b0, b1);
            PROCP(p + 2, a0, a1);
            PROCP(p + 3, b0, b1);
            PROCP(p + 4, a0, a1);
            PROCP(p + 5, b0, b1);
            PROCP(p + 6, a0, a1);
            PROCP(p + 7, b0, b1);
        }
        for (; p < np; p++){
            PROCP(p, a0, a1);
        }
    }
    a0 += b0; a1 += b1;
    a0 += __shfl_xor(a0, 32, 64);
    a1 += __shfl_xor(a1, 32, 64);
    if (lane < 32){
        h2 o; o.x = (_Float16)a0; o.y = (_Float16)a1;
        *(unsigned int*)&agg[((size_t)(g * NATOMS + nn) << 6) + fo] = __builtin_bit_cast(unsigned int, o);
    }
}

// ---------------- barrier-free MFMA node GEMMs (wave-private 16-row tiles).
// mode 1: h += ssp(agg@w2+b2)@w3+b3 ; x = h_new @ w1n.   mode 0: x = h @ w1n.
__global__ __launch_bounds__(256) void k_updlin(const __half* __restrict__ agg, const __half* __restrict__ w2t,
                                                const float* __restrict__ b2, const __half* __restrict__ w3t,
                                                const float* __restrict__ b3, const __half* __restrict__ w1nt,
                                                __half* __restrict__ h, __half* __restrict__ x,
                                                int mode, int has_x){
    __shared__ _Float16 T[4][16 * 72];      // per-wave 16x64 tile, stride 72 (16B-aligned rows)
    int t = threadIdx.x;
    int w = t >> 6, lane = t & 63;
    int m = lane & 15, kg = lane >> 4;
    size_t base = (size_t)blockIdx.x * 64 + ((size_t)w << 4);   // global node row of this wave's tile
    _Float16* Tw = T[w];
    int lr = lane >> 2, lc = (lane & 3) << 4;    // linear chunk: row lr, cols lc..lc+15

    const _Float16* aggh = (const _Float16*)agg;
    const _Float16* w2h  = (const _Float16*)w2t;
    const _Float16* w3h  = (const _Float16*)w3t;
    const _Float16* w1h  = (const _Float16*)w1nt;
    _Float16* hh = (_Float16*)h;
    _Float16* xh = (_Float16*)x;

    f32x4 acc[4];

#define GEMM_GLOBAL_A(AP, WT) { \
    acc[0] = (f32x4)0.f; acc[1] = (f32x4)0.f; acc[2] = (f32x4)0.f; acc[3] = (f32x4)0.f; \
    _Pragma("unroll") \
    for (int kh = 0; kh < 2; kh++){ \
        f16x8 av = *(const f16x8*)&(AP)[((size_t)m << 6) + kh * 32 + kg * 8]; \
        _Pragma("unroll") \
        for (int cb = 0; cb < 4; cb++){ \
            f16x8 bv = *(const f16x8*)&(WT)[(size_t)((cb << 4) + m) * 64 + kh * 32 + kg * 8]; \
            acc[cb] = __builtin_amdgcn_mfma_f32_16x16x32_f16(av, bv, acc[cb], 0, 0, 0); \
        } \
    } }

#define GEMM_LDS_A(WT) { \
    acc[0] = (f32x4)0.f; acc[1] = (f32x4)0.f; acc[2] = (f32x4)0.f; acc[3] = (f32x4)0.f; \
    _Pragma("unroll") \
    for (int kh = 0; kh < 2; kh++){ \
        f16x8 av = *(const f16x8*)&Tw[m * 72 + kh * 32 + kg * 8]; \
        _Pragma("unroll") \
        for (int cb = 0; cb < 4; cb++){ \
            f16x8 bv = *(const f16x8*)&(WT)[(size_t)((cb << 4) + m) * 64 + kh * 32 + kg * 8]; \
            acc[cb] = __builtin_amdgcn_mfma_f32_16x16x32_f16(av, bv, acc[cb], 0, 0, 0); \
        } \
    } }

#define SCATTER_RAW() { \
    _Pragma("unroll") \
    for (int cb = 0; cb < 4; cb++){ \
        _Pragma("unroll") \
        for (int v = 0; v < 4; v++) \
            Tw[((kg << 2) + v) * 72 + (cb << 4) + m] = (_Float16)acc[cb][v]; \
    } }

    if (mode == 0){
        GEMM_GLOBAL_A(hh + base * 64, w1h);
        SCATTER_RAW();
        f16x8 c0 = *(const f16x8*)&Tw[lr * 72 + lc];
        f16x8 c1 = *(const f16x8*)&Tw[lr * 72 + lc + 8];
        *(f16x8*)&xh[(base + lr) * 64 + lc]     = c0;
        *(f16x8*)&xh[(base + lr) * 64 + lc + 8] = c1;
        return;
    }

    // GEMM1: t = ssp(agg @ w2 + b2) -> Tw (scatter with op)
    GEMM_GLOBAL_A(aggh + base * 64, w2h);
    #pragma unroll
    for (int cb = 0; cb < 4; cb++){
        float bv = b2[(cb << 4) + m];
        #pragma unroll
        for (int v = 0; v < 4; v++)
            Tw[((kg << 2) + v) * 72 + (cb << 4) + m] = (_Float16)sspf(acc[cb][v] + bv);
    }

    // GEMM2: C = t @ w3 ; h_new = C + b3 + h_old (coalesced via linear chunks)
    GEMM_LDS_A(w3h);
    SCATTER_RAW();
    {
        f16x8 c0 = *(const f16x8*)&Tw[lr * 72 + lc];
        f16x8 c1 = *(const f16x8*)&Tw[lr * 72 + lc + 8];
        float bb[16];
        *(float4*)&bb[0]  = *(const float4*)&b3[lc];
        *(float4*)&bb[4]  = *(const float4*)&b3[lc + 4];
        *(float4*)&bb[8]  = *(const float4*)&b3[lc + 8];
        *(float4*)&bb[12] = *(const float4*)&b3[lc + 12];
        f16x8 h0 = *(const f16x8*)&hh[(base + lr) * 64 + lc];
        f16x8 h1 = *(const f16x8*)&hh[(base + lr) * 64 + lc + 8];
        f16x8 n0, n1;
        #pragma unroll
        for (int j = 0; j < 8; j++){
            n0[j] = (_Float16)((float)c0[j] + bb[j]     + (float)h0[j]);
            n1[j] = (_Float16)((float)c1[j] + bb[8 + j] + (float)h1[j]);
        }
        *(f16x8*)&hh[(base + lr) * 64 + lc]     = n0;
        *(f16x8*)&hh[(base + lr) * 64 + lc + 8] = n1;
        *(f16x8*)&Tw[lr * 72 + lc]     = n0;
        *(f16x8*)&Tw[lr * 72 + lc + 8] = n1;
    }
    if (!has_x) return;

    // GEMM3: x = h_new @ w1_next
    GEMM_LDS_A(w1h);
    SCATTER_RAW();
    {
        f16x8 c0 = *(const f16x8*)&Tw[lr * 72 + lc];
        f16x8 c1 = *(const f16x8*)&Tw[lr * 72 + lc + 8];
        *(f16x8*)&xh[(base + lr) * 64 + lc]     = c0;
        *(f16x8*)&xh[(base + lr) * 64 + lc + 8] = c1;
    }
#undef GEMM_GLOBAL_A
#undef GEMM_LDS_A
#undef SCATTER_RAW
}

// ---------------- readout: eout[g][f] = sum_n h[n][f]  (h fp16)
__global__ __launch_bounds__(256) void k_readout(const __half* __restrict__ h, float* __restrict__ eout){
    int f  = threadIdx.x & 63;
    int wq = threadIdx.x >> 6;
    int nodeBase = blockIdx.x * 256 + wq * 64;
    float acc = 0.f;
    #pragma unroll 4
    for (int j = 0; j < 64; j++) acc += __half2float(h[(size_t)(nodeBase + j) * 64 + f]);
    int g = nodeBase >= NATOMS;
    atomicAdd(&eout[g * 64 + f], acc);
}

// ---------------- head: fc1 -> PReLU -> fc2 -> exp
__global__ __launch_bounds__(64) void k_final(const float* __restrict__ eout, const float* __restrict__ addf,
                                              const float* __restrict__ fc1w, const float* __restrict__ fc1b,
                                              const float* __restrict__ pra, const float* __restrict__ fc2w,
                                              const float* __restrict__ fc2b, float* __restrict__ out){
    int f = threadIdx.x;
    float xv = fc1b[f];
    const float inv = 1.0f / 256.0f;
    for (int k = 0; k < 64; k++)  xv = fmaf(eout[k] * inv,      fc1w[k * 64 + f],        xv);
    for (int k = 0; k < 64; k++)  xv = fmaf(eout[64 + k] * inv, fc1w[(64 + k) * 64 + f], xv);
    xv = fmaf(addf[0], fc1w[128 * 64 + f], xv);
    xv = fmaf(addf[1], fc1w[129 * 64 + f], xv);
    float a = pra[0];
    xv = (xv >= 0.f) ? xv : a * xv;
    float s = xv * fc2w[f];
    #pragma unroll
    for (int m = 32; m >= 1; m >>= 1) s += __shfl_xor(s, m, 64);
    if (f == 0) out[0] = expf(s + fc2b[0]);
}

extern "C" void kernel_launch(void* const* d_in, const int* in_sizes, int n_in,
                              void* d_out, int out_size, void* d_ws, size_t ws_size,
                              hipStream_t stream){
    const int*   zA    = (const int*)  d_in[0];
    const float* posA  = (const float*)d_in[1];
    const int*   edgeA = (const int*)  d_in[3];
    const int*   zG    = (const int*)  d_in[4];
    const float* posG  = (const float*)d_in[5];
    const int*   edgeG = (const int*)  d_in[7];
    const float* addf  = (const float*)d_in[8];
    const float* emb   = (const float*)d_in[9];
    const float* mw1   = (const float*)d_in[10];
    const float* mb1   = (const float*)d_in[11];
    const float* mw2   = (const float*)d_in[12];
    const float* mb2   = (const float*)d_in[13];
    const float* l1w   = (const float*)d_in[14];
    const float* l2w   = (const float*)d_in[15];
    const float* l2b   = (const float*)d_in[16];
    const float* l3w   = (const float*)d_in[17];
    const float* l3b   = (const float*)d_in[18];
    const float* fc1w  = (const float*)d_in[19];
    const float* fc1b  = (const float*)d_in[20];
    const float* pra   = (const float*)d_in[21];
    const float* fc2w  = (const float*)d_in[22];
    const float* fc2b  = (const float*)d_in[23];
    float* out = (float*)d_out;

    // workspace layout (~32 MB)
    char* p = (char*)d_ws;
    auto alloc = [&](size_t bytes)->char*{ char* r = p; p += (bytes + 255) & ~(size_t)255; return r; };
    float*   tabf   = (float*)  alloc((size_t)NINT * TK * 64 * 4);   // 1.6 MB
    __half2* tab2   = (__half2*)alloc((size_t)NINT * TK * 64 * 4);   // 1.6 MB
    uint2*   meta8  = (uint2*)  alloc((size_t)2 * NEDGE * 8);        // 8.4 MB
    uint2*   metaF  = (uint2*)  alloc((size_t)2 * NEDGE * 8);        // 8.4 MB
    int*     rowptr = (int*)    alloc((size_t)2 * (NATOMS + 1) * 4);
    int*     gcur   = (int*)    alloc((size_t)2 * NBUCK * 4);
    int*     bhist  = (int*)    alloc((size_t)2 * NBUCK * 4);
    int*     bstart = (int*)    alloc((size_t)2 * (NBUCK + 1) * 4);
    __half*  h      = (__half*) alloc((size_t)2 * NATOMS * 64 * 2);  // 4.2 MB
    __half*  x      = (__half*) alloc((size_t)2 * NATOMS * 64 * 2);  // 4.2 MB
    __half*  agg    = (__half*) alloc((size_t)2 * NATOMS * 64 * 2);  // 4.2 MB
    __half*  wT     = (__half*) alloc((size_t)18 * 4096 * 2);        // 147 KB
    float*   eout   = (float*)  alloc(128 * 4);

    hipMemsetAsync(bhist, 0, (size_t)2 * NBUCK * 4, stream);
    hipMemsetAsync(eout, 0, 128 * 4, stream);

    k_embed <<<(2 * NATOMS * 32) / 256, 256, 0, stream>>>(zA, zG, emb, h);
    k_bhist <<<256, 256, 0, stream>>>(edgeA, edgeG, bhist);
    k_bscan <<<2, 512, 0, stream>>>(bhist, bstart, gcur);
    k_place1<<<256,  256, 0, stream>>>(edgeA, edgeG, posA, posG, gcur, meta8);
    k_place2<<<1024, 256, 0, stream>>>(meta8, bstart, rowptr, metaF);
    k_tables<<<(NINT * TK) / 4,        256, 0, stream>>>(mw1, mb1, mw2, mb2, tabf);
    k_pack  <<<(NINT * TK * 64) / 256, 256, 0, stream>>>(tabf, tab2);
    k_wpack <<<(18 * 4096) / 256,      256, 0, stream>>>(l1w, l2w, l3w, wT);

    const __half* w1t0 = wT;
    // lin1 (mode 0)
    k_updlin<<<(2 * NATOMS) / 64, 256, 0, stream>>>(agg, wT, l2b, wT, l3b, w1t0, h, x, 0, 1);
    for (int i = 0; i < NINT; i++){
        k_agg<<<(2 * NATOMS) / 4, 256, 0, stream>>>(x, tab2 + (size_t)i * TK * 64, metaF, rowptr, agg);
        int has_x = (i < NINT - 1);
        const __half* w2t  = wT + (size_t)(6 + i) * 4096;
        const __half* w3t  = wT + (size_t)(12 + i) * 4096;
        const __half* w1nt = wT + (size_t)(has_x ? (i + 1) : 0) * 4096;
        k_updlin<<<(2 * NATOMS) / 64, 256, 0, stream>>>(agg, w2t, l2b + i * 64,
                                                        w3t, l3b + i * 64, w1nt, h, x, 1, has_x);
    }

    k_readout<<<(2 * NATOMS) / 256, 256, 0, stream>>>(h, eout);
    k_final  <<<1, 64, 0, stream>>>(eout, addf, fc1w, fc1b, pra, fc2w, fc2b, out);
}